// Round 2
// baseline (2063.710 us; speedup 1.0000x reference)
//
#include <hip/hip_runtime.h>
#include <math.h>

#define B_  2
#define S_  2048
#define D_  1024
#define H_  16
#define HD_ 64
#define NT_ (S_/64)          // 32 key tiles
#define SCALE_ 0.125f        // 1/sqrt(64)

// ---------------------------------------------------------------------------
// Projection GEMM: P[m,n] = sum_k X[m,k] * W[n,k]   (x @ w.T)
// X: [M=B*S, K=D] row-major. W: [N=D, K=D] row-major.
// Output written in [b, h, s, hd] layout: P[((b*H+h)*S + s)*HD + hd].
// 64x64 tile per block, 256 threads, 4x4 micro-tile, BK=16.
// LDS tiles stored transposed [k][row]: staging covers 64 rows x 16 k per
// iter = 256 threads x 4 floats.
// ---------------------------------------------------------------------------
__global__ __launch_bounds__(256)
void proj_kernel(const float* __restrict__ Q, const float* __restrict__ K,
                 const float* __restrict__ V, const float* __restrict__ WQ,
                 const float* __restrict__ WK, const float* __restrict__ WV,
                 float* __restrict__ QP, float* __restrict__ KP,
                 float* __restrict__ VP)
{
    const int which = blockIdx.z;
    const float* X = (which == 0) ? Q  : (which == 1) ? K  : V;
    const float* W = (which == 0) ? WQ : (which == 1) ? WK : WV;
    float*       P = (which == 0) ? QP : (which == 1) ? KP : VP;

    const int n0 = blockIdx.x * 64;   // output column tile (head dim space)
    const int m0 = blockIdx.y * 64;   // row tile (b*s space)

    __shared__ float Xs[16][68];      // [k][r]; row stride 272 B = 17*16 (aligned)
    __shared__ float Ws[16][68];      // [k][c]

    const int tid = threadIdx.x;
    const int tx  = tid & 15, ty = tid >> 4;
    const int lr  = tid >> 2;         // loader row 0..63
    const int lk4 = (tid & 3) * 4;    // loader k offset 0,4,8,12

    float acc[4][4] = {};

    for (int k0 = 0; k0 < D_; k0 += 16) {
        float4 xv = *(const float4*)&X[(size_t)(m0 + lr) * D_ + k0 + lk4];
        float4 wv = *(const float4*)&W[(size_t)(n0 + lr) * D_ + k0 + lk4];
        __syncthreads();              // prior iteration's LDS reads complete
        Xs[lk4 + 0][lr] = xv.x; Xs[lk4 + 1][lr] = xv.y;
        Xs[lk4 + 2][lr] = xv.z; Xs[lk4 + 3][lr] = xv.w;
        Ws[lk4 + 0][lr] = wv.x; Ws[lk4 + 1][lr] = wv.y;
        Ws[lk4 + 2][lr] = wv.z; Ws[lk4 + 3][lr] = wv.w;
        __syncthreads();
        #pragma unroll
        for (int kk = 0; kk < 16; ++kk) {
            float4 a = *(const float4*)&Xs[kk][ty * 4];
            float4 b = *(const float4*)&Ws[kk][tx * 4];
            float av[4] = {a.x, a.y, a.z, a.w};
            float bv[4] = {b.x, b.y, b.z, b.w};
            #pragma unroll
            for (int i = 0; i < 4; ++i)
                #pragma unroll
                for (int j = 0; j < 4; ++j)
                    acc[i][j] += av[i] * bv[j];
        }
    }

    #pragma unroll
    for (int i = 0; i < 4; ++i) {
        int m = m0 + ty * 4 + i;
        int b = m >> 11;              // / S_
        int s = m & (S_ - 1);
        int n = n0 + tx * 4;
        int h  = n >> 6;              // / HD_
        int hd = n & 63;
        float4 o = make_float4(acc[i][0], acc[i][1], acc[i][2], acc[i][3]);
        *(float4*)&P[(((size_t)b * H_ + h) * S_ + s) * HD_ + hd] = o;
    }
}

// ---------------------------------------------------------------------------
// Per-64-key-tile V column sums: TS[bh][t][c] = sum_{j in tile t} VP[bh][j][c]
// ---------------------------------------------------------------------------
__global__ __launch_bounds__(64)
void vtilesum_kernel(const float* __restrict__ VP, float* __restrict__ TS)
{
    const int t = blockIdx.x, bh = blockIdx.y, c = threadIdx.x;
    const float* base = VP + ((size_t)bh * S_ + t * 64) * HD_ + c;
    float acc = 0.f;
    #pragma unroll
    for (int j = 0; j < 64; ++j) acc += base[(size_t)j * HD_];
    TS[((size_t)bh * NT_ + t) * HD_ + c] = acc;
}

// Suffix sums over tiles: SUF[bh][t][c] = sum_{t' >= t} TS[bh][t'][c]; SUF[NT_]=0
__global__ __launch_bounds__(64)
void vsuffix_kernel(const float* __restrict__ TS, float* __restrict__ SUF)
{
    const int bh = blockIdx.x, c = threadIdx.x;
    float acc = 0.f;
    SUF[((size_t)bh * (NT_ + 1) + NT_) * HD_ + c] = 0.f;
    for (int t = NT_ - 1; t >= 0; --t) {
        acc += TS[((size_t)bh * NT_ + t) * HD_ + c];
        SUF[((size_t)bh * (NT_ + 1) + t) * HD_ + c] = acc;
    }
}

// ---------------------------------------------------------------------------
// Flash-style attention with the reference's "zeroed upper triangle" softmax:
// keys j<=i contribute exp(s_ij - m); keys j>i contribute exp(0 - m).
// Strictly-beyond-diagonal tiles handled analytically via V suffix sums.
// One block per (q-tile of 64, bh). 256 threads, 4x4 micro-tiles.
// Tile loaders: 64 rows x 64 dims = 256 threads x 4 float4 (fixed in R2 —
// R1 only loaded dims 0..15).
// ---------------------------------------------------------------------------
__global__ __launch_bounds__(256)
void attn_kernel(const float* __restrict__ QP, const float* __restrict__ KP,
                 const float* __restrict__ VP, const float* __restrict__ SUF,
                 float* __restrict__ OUT)
{
    const int tq = (int)gridDim.x - 1 - (int)blockIdx.x;  // heavy blocks first
    const int bh = blockIdx.y;
    const int b  = bh >> 4, h = bh & 15;
    const int q0 = tq * 64;

    __shared__ float Qs[64][68];      // [d][r]   transposed
    __shared__ float KsPs[64][68];    // [d][c] during QK; [key][r] as P after
    __shared__ float Vs[64][68];      // [key][d] row-major

    const int tid = threadIdx.x;
    const int tx  = tid & 15, ty = tid >> 4;
    const int lr  = tid >> 2;         // loader row 0..63
    const int lc  = (tid & 3) * 16;   // loader dim base 0,16,32,48

    const float* Qb = QP + (size_t)bh * S_ * HD_;
    const float* Kb = KP + (size_t)bh * S_ * HD_;
    const float* Vb = VP + (size_t)bh * S_ * HD_;

    {   // load full Q tile transposed: 4 float4 per thread (16 dims)
        #pragma unroll
        for (int c = 0; c < 4; ++c) {
            float4 qv = *(const float4*)&Qb[(size_t)(q0 + lr) * HD_ + lc + c * 4];
            Qs[lc + c * 4 + 0][lr] = qv.x; Qs[lc + c * 4 + 1][lr] = qv.y;
            Qs[lc + c * 4 + 2][lr] = qv.z; Qs[lc + c * 4 + 3][lr] = qv.w;
        }
    }

    float o[4][4] = {};
    float m_i[4], l_i[4];
    #pragma unroll
    for (int i = 0; i < 4; ++i) { m_i[i] = -1e30f; l_i[i] = 0.f; }

    for (int t = 0; t <= tq; ++t) {
        const int k0t = t * 64;
        float4 kv[4], vv[4];
        #pragma unroll
        for (int c = 0; c < 4; ++c) {
            kv[c] = *(const float4*)&Kb[(size_t)(k0t + lr) * HD_ + lc + c * 4];
            vv[c] = *(const float4*)&Vb[(size_t)(k0t + lr) * HD_ + lc + c * 4];
        }
        __syncthreads();   // (A) prior iteration's PV reads done
        #pragma unroll
        for (int c = 0; c < 4; ++c) {
            KsPs[lc + c * 4 + 0][lr] = kv[c].x; KsPs[lc + c * 4 + 1][lr] = kv[c].y;
            KsPs[lc + c * 4 + 2][lr] = kv[c].z; KsPs[lc + c * 4 + 3][lr] = kv[c].w;
            *(float4*)&Vs[lr][lc + c * 4] = vv[c];
        }
        __syncthreads();   // (B) tiles visible

        // ---- S = Q K^T (outer product over d) ----
        float s[4][4] = {};
        #pragma unroll
        for (int d = 0; d < 64; ++d) {
            float4 a  = *(const float4*)&Qs[d][ty * 4];
            float4 bq = *(const float4*)&KsPs[d][tx * 4];
            float av[4] = {a.x, a.y, a.z, a.w};
            float bv[4] = {bq.x, bq.y, bq.z, bq.w};
            #pragma unroll
            for (int i = 0; i < 4; ++i)
                #pragma unroll
                for (int j = 0; j < 4; ++j)
                    s[i][j] += av[i] * bv[j];
        }

        // ---- scale + zero-mask (reference zeroes, doesn't -inf) ----
        #pragma unroll
        for (int i = 0; i < 4; ++i) {
            int ig = q0 + ty * 4 + i;
            #pragma unroll
            for (int j = 0; j < 4; ++j) {
                int jg = k0t + tx * 4 + j;
                s[i][j] = (jg <= ig) ? s[i][j] * SCALE_ : 0.f;
            }
        }

        // ---- online softmax (row groups = 16 lanes, shfl_xor reductions) ----
        #pragma unroll
        for (int i = 0; i < 4; ++i) {
            float mx = fmaxf(fmaxf(s[i][0], s[i][1]), fmaxf(s[i][2], s[i][3]));
            mx = fmaxf(mx, __shfl_xor(mx, 1));
            mx = fmaxf(mx, __shfl_xor(mx, 2));
            mx = fmaxf(mx, __shfl_xor(mx, 4));
            mx = fmaxf(mx, __shfl_xor(mx, 8));
            float mn    = fmaxf(m_i[i], mx);
            float alpha = expf(m_i[i] - mn);
            m_i[i] = mn;
            float ps = 0.f;
            #pragma unroll
            for (int j = 0; j < 4; ++j) { s[i][j] = expf(s[i][j] - mn); ps += s[i][j]; }
            ps += __shfl_xor(ps, 1); ps += __shfl_xor(ps, 2);
            ps += __shfl_xor(ps, 4); ps += __shfl_xor(ps, 8);
            l_i[i] = l_i[i] * alpha + ps;
            #pragma unroll
            for (int j = 0; j < 4; ++j) o[i][j] *= alpha;
        }

        __syncthreads();   // (C) all QK reads of KsPs done before P overwrite
        #pragma unroll
        for (int i = 0; i < 4; ++i)
            #pragma unroll
            for (int j = 0; j < 4; ++j)
                KsPs[tx * 4 + j][ty * 4 + i] = s[i][j];   // P transposed [key][r]
        __syncthreads();   // (D) P visible

        // ---- O += P V (outer product over key j) ----
        #pragma unroll
        for (int j = 0; j < 64; ++j) {
            float4 a  = *(const float4*)&KsPs[j][ty * 4];
            float4 v4 = *(const float4*)&Vs[j][tx * 4];
            float av[4] = {a.x, a.y, a.z, a.w};
            float bv[4] = {v4.x, v4.y, v4.z, v4.w};
            #pragma unroll
            for (int i = 0; i < 4; ++i)
                #pragma unroll
                for (int jj = 0; jj < 4; ++jj)
                    o[i][jj] += av[i] * bv[jj];
        }
    }

    // ---- masked-suffix contribution + normalize + store ----
    const int cnt = S_ - (q0 + 64);   // fully-masked keys beyond diagonal tile
    const float* suf = SUF + ((size_t)bh * (NT_ + 1) + (tq + 1)) * HD_;
    float4 sv = *(const float4*)&suf[tx * 4];
    float sva[4] = {sv.x, sv.y, sv.z, sv.w};

    #pragma unroll
    for (int i = 0; i < 4; ++i) {
        float w     = expf(-m_i[i]);               // e^{0 - m}
        float denom = l_i[i] + w * (float)cnt;
        float inv   = 1.0f / denom;
        int   srow  = q0 + ty * 4 + i;
        float4 ov;
        ov.x = (o[i][0] + w * sva[0]) * inv;
        ov.y = (o[i][1] + w * sva[1]) * inv;
        ov.z = (o[i][2] + w * sva[2]) * inv;
        ov.w = (o[i][3] + w * sva[3]) * inv;
        *(float4*)&OUT[((size_t)b * S_ + srow) * D_ + h * HD_ + tx * 4] = ov;
    }
}

// ---------------------------------------------------------------------------
extern "C" void kernel_launch(void* const* d_in, const int* in_sizes, int n_in,
                              void* d_out, int out_size, void* d_ws, size_t ws_size,
                              hipStream_t stream)
{
    (void)in_sizes; (void)n_in; (void)out_size; (void)ws_size;
    const float* q  = (const float*)d_in[0];
    const float* k  = (const float*)d_in[1];
    const float* v  = (const float*)d_in[2];
    const float* wq = (const float*)d_in[3];
    const float* wk = (const float*)d_in[4];
    const float* wv = (const float*)d_in[5];
    float* out = (float*)d_out;

    float* ws = (float*)d_ws;
    const size_t PROJ = (size_t)B_ * H_ * S_ * HD_;     // 4,194,304 floats
    float* QP  = ws;
    float* KP  = ws + PROJ;
    float* VP  = ws + 2 * PROJ;
    float* TS  = ws + 3 * PROJ;                         // 32*32*64 floats
    float* SUF = TS + (size_t)B_ * H_ * NT_ * HD_;      // 32*33*64 floats

    proj_kernel<<<dim3(D_ / 64, (B_ * S_) / 64, 3), 256, 0, stream>>>(
        q, k, v, wq, wk, wv, QP, KP, VP);
    vtilesum_kernel<<<dim3(NT_, B_ * H_), 64, 0, stream>>>(VP, TS);
    vsuffix_kernel<<<B_ * H_, 64, 0, stream>>>(TS, SUF);
    attn_kernel<<<dim3(NT_, B_ * H_), 256, 0, stream>>>(QP, KP, VP, SUF, out);
}

// Round 3
// 405.039 us; speedup vs baseline: 5.0951x; 5.0951x over previous
//
#include <hip/hip_runtime.h>
#include <math.h>

#define B_  2
#define S_  2048
#define D_  1024
#define H_  16
#define HD_ 64
#define NT_ (S_/64)          // 32 key tiles
#define SCALE_ 0.125f        // 1/sqrt(64)

typedef __attribute__((ext_vector_type(8))) short bf16x8;
typedef __attribute__((ext_vector_type(4))) float f32x4;
typedef unsigned short u16;

__device__ inline u16 f2bf(float f) {
    union { float f; unsigned u; } c; c.f = f;
    unsigned u = c.u;
    u += 0x7fffu + ((u >> 16) & 1u);       // round-to-nearest-even
    return (u16)(u >> 16);
}
__device__ inline float bf2f(u16 h) {
    union { unsigned u; float f; } c; c.u = ((unsigned)h) << 16;
    return c.f;
}

// ---------------------------------------------------------------------------
// Projection GEMM via bf16 MFMA: P[m,n] = sum_k X[m,k] * W[n,k]  (x @ w.T)
// 64x64 tile, 256 thr (4 waves), BK=64. Q/K: single bf16 product (score-path
// errors self-damp through softmax). V: hi/lo split, 3 products, output
// stored as (vhi, vlo) bf16 pair so the PV path is ~exact.
// Output layout [b,h,s,hd].
// ---------------------------------------------------------------------------
__global__ __launch_bounds__(256)
void proj_mfma(const float* __restrict__ Qi, const float* __restrict__ Ki,
               const float* __restrict__ Vi, const float* __restrict__ WQ,
               const float* __restrict__ WK, const float* __restrict__ WV,
               u16* __restrict__ QP, u16* __restrict__ KP,
               u16* __restrict__ VPhi, u16* __restrict__ VPlo)
{
    const int which = blockIdx.z;
    const float* X = (which == 0) ? Qi : (which == 1) ? Ki : Vi;
    const float* W = (which == 0) ? WQ : (which == 1) ? WK : WV;
    const bool isV = (which == 2);

    __shared__ u16 Xhi[64][72], Whi[64][72];   // [row][k], 144B rows (16B-aligned)
    __shared__ u16 Xlo[64][72], Wlo[64][72];   // only used for V

    const int tid  = threadIdx.x;
    const int w    = tid >> 6;
    const int lane = tid & 63;
    const int quad = lane >> 4;
    const int lr   = lane & 15;
    const int r    = tid >> 2;          // loader row 0..63
    const int kb   = (tid & 3) * 16;    // loader k base
    const int m0   = blockIdx.y * 64;
    const int n0   = blockIdx.x * 64;

    f32x4 acc[4];
    #pragma unroll
    for (int n = 0; n < 4; ++n) acc[n] = (f32x4){0.f, 0.f, 0.f, 0.f};

    for (int k0 = 0; k0 < D_; k0 += 64) {
        float4 xv[4], wv[4];
        #pragma unroll
        for (int c = 0; c < 4; ++c) {
            xv[c] = *(const float4*)&X[(size_t)(m0 + r) * D_ + k0 + kb + c * 4];
            wv[c] = *(const float4*)&W[(size_t)(n0 + r) * D_ + k0 + kb + c * 4];
        }
        __syncthreads();                 // prior iteration's frag reads done
        #pragma unroll
        for (int c = 0; c < 4; ++c) {
            float xe[4] = {xv[c].x, xv[c].y, xv[c].z, xv[c].w};
            float we[4] = {wv[c].x, wv[c].y, wv[c].z, wv[c].w};
            u16 hx[4], hw[4];
            #pragma unroll
            for (int e = 0; e < 4; ++e) { hx[e] = f2bf(xe[e]); hw[e] = f2bf(we[e]); }
            uint2 px, pw;
            px.x = (unsigned)hx[0] | ((unsigned)hx[1] << 16);
            px.y = (unsigned)hx[2] | ((unsigned)hx[3] << 16);
            pw.x = (unsigned)hw[0] | ((unsigned)hw[1] << 16);
            pw.y = (unsigned)hw[2] | ((unsigned)hw[3] << 16);
            *(uint2*)&Xhi[r][kb + c * 4] = px;
            *(uint2*)&Whi[r][kb + c * 4] = pw;
            if (isV) {
                u16 lx[4], lw[4];
                #pragma unroll
                for (int e = 0; e < 4; ++e) {
                    lx[e] = f2bf(xe[e] - bf2f(hx[e]));
                    lw[e] = f2bf(we[e] - bf2f(hw[e]));
                }
                uint2 qx, qw;
                qx.x = (unsigned)lx[0] | ((unsigned)lx[1] << 16);
                qx.y = (unsigned)lx[2] | ((unsigned)lx[3] << 16);
                qw.x = (unsigned)lw[0] | ((unsigned)lw[1] << 16);
                qw.y = (unsigned)lw[2] | ((unsigned)lw[3] << 16);
                *(uint2*)&Xlo[r][kb + c * 4] = qx;
                *(uint2*)&Wlo[r][kb + c * 4] = qw;
            }
        }
        __syncthreads();

        #pragma unroll
        for (int ch = 0; ch < 2; ++ch) {
            bf16x8 ah = *(const bf16x8*)&Xhi[w * 16 + lr][ch * 32 + quad * 8];
            bf16x8 al;
            if (isV) al = *(const bf16x8*)&Xlo[w * 16 + lr][ch * 32 + quad * 8];
            #pragma unroll
            for (int n = 0; n < 4; ++n) {
                bf16x8 bh = *(const bf16x8*)&Whi[n * 16 + lr][ch * 32 + quad * 8];
                acc[n] = __builtin_amdgcn_mfma_f32_16x16x32_bf16(ah, bh, acc[n], 0, 0, 0);
                if (isV) {
                    bf16x8 bl = *(const bf16x8*)&Wlo[n * 16 + lr][ch * 32 + quad * 8];
                    acc[n] = __builtin_amdgcn_mfma_f32_16x16x32_bf16(ah, bl, acc[n], 0, 0, 0);
                    acc[n] = __builtin_amdgcn_mfma_f32_16x16x32_bf16(al, bh, acc[n], 0, 0, 0);
                }
            }
        }
    }

    // epilogue: C layout row=quad*4+i (m), col=lr (n within group)
    u16* Pout = (which == 0) ? QP : KP;
    #pragma unroll
    for (int n = 0; n < 4; ++n) {
        #pragma unroll
        for (int i = 0; i < 4; ++i) {
            int m  = m0 + w * 16 + quad * 4 + i;
            int b  = m >> 11;
            int s  = m & (S_ - 1);
            int h  = n0 >> 6;                 // tile spans exactly one head
            int hd = n * 16 + lr;
            size_t idx = (((size_t)b * H_ + h) * S_ + s) * HD_ + hd;
            float v = acc[n][i];
            if (!isV) {
                Pout[idx] = f2bf(v);
            } else {
                u16 hv = f2bf(v);
                VPhi[idx] = hv;
                VPlo[idx] = f2bf(v - bf2f(hv));
            }
        }
    }
}

// ---------------------------------------------------------------------------
// Per-64-key-tile V column sums (fp32 from vhi+vlo)
// ---------------------------------------------------------------------------
__global__ __launch_bounds__(64)
void vtilesum_kernel(const u16* __restrict__ VPhi, const u16* __restrict__ VPlo,
                     float* __restrict__ TS)
{
    const int t = blockIdx.x, bh = blockIdx.y, c = threadIdx.x;
    const size_t base = ((size_t)bh * S_ + t * 64) * HD_ + c;
    float acc = 0.f;
    #pragma unroll
    for (int j = 0; j < 64; ++j)
        acc += bf2f(VPhi[base + (size_t)j * HD_]) + bf2f(VPlo[base + (size_t)j * HD_]);
    TS[((size_t)bh * NT_ + t) * HD_ + c] = acc;
}

__global__ __launch_bounds__(64)
void vsuffix_kernel(const float* __restrict__ TS, float* __restrict__ SUF)
{
    const int bh = blockIdx.x, c = threadIdx.x;
    float acc = 0.f;
    SUF[((size_t)bh * (NT_ + 1) + NT_) * HD_ + c] = 0.f;
    for (int t = NT_ - 1; t >= 0; --t) {
        acc += TS[((size_t)bh * NT_ + t) * HD_ + c];
        SUF[((size_t)bh * (NT_ + 1) + t) * HD_ + c] = acc;
    }
}

// ---------------------------------------------------------------------------
// MFMA flash attention, zeroed-upper-triangle softmax + V-suffix trick.
// 4 waves x 16-row q-bands; Q frags in registers; K and V^T staged in LDS
// (bf16); softmax in-wave on C-layout frags; P (hi/lo bf16) round-trips LDS
// per band (no cross-wave hazard). PV = Phi*Vhi + Phi*Vlo + Plo*Vhi.
// ---------------------------------------------------------------------------
__global__ __launch_bounds__(256)
void attn_mfma(const u16* __restrict__ QP, const u16* __restrict__ KP,
               const u16* __restrict__ VPhi, const u16* __restrict__ VPlo,
               const float* __restrict__ SUF, float* __restrict__ OUT)
{
    const int tq = (int)gridDim.x - 1 - (int)blockIdx.x;   // heavy blocks first
    const int bh = blockIdx.y;
    const int b  = bh >> 4, h = bh & 15;
    const int q0 = tq * 64;

    __shared__ u16 Ks[64][72];       // [key][d]
    __shared__ u16 Vthi[64][72];     // [vd][key]  (transposed)
    __shared__ u16 Vtlo[64][72];
    __shared__ u16 Phi[64][72];      // [q_local][key]
    __shared__ u16 Plo[64][72];

    const int tid  = threadIdx.x;
    const int w    = tid >> 6;
    const int lane = tid & 63;
    const int quad = lane >> 4;
    const int lr   = lane & 15;

    const u16* Qb  = QP   + (size_t)bh * S_ * HD_;
    const u16* Kb  = KP   + (size_t)bh * S_ * HD_;
    const u16* Vhb = VPhi + (size_t)bh * S_ * HD_;
    const u16* Vlb = VPlo + (size_t)bh * S_ * HD_;

    // Q A-frags resident in registers: A[m=lr][k=quad*8+j], 2 K-chunks
    bf16x8 qf[2];
    #pragma unroll
    for (int ch = 0; ch < 2; ++ch)
        qf[ch] = *(const bf16x8*)(Qb + (size_t)(q0 + w * 16 + lr) * HD_ + ch * 32 + quad * 8);

    f32x4 of[4];
    #pragma unroll
    for (int n = 0; n < 4; ++n) of[n] = (f32x4){0.f, 0.f, 0.f, 0.f};
    float m_i[4], l_i[4];
    #pragma unroll
    for (int i = 0; i < 4; ++i) { m_i[i] = -1e30f; l_i[i] = 0.f; }

    // staging maps
    const int krow = tid >> 3, kch = tid & 7;          // K: [row][16B chunk]
    const int vkey = lr * 4 + quad;                    // V: lane's key, band = w*16
    const int vb   = w * 16;

    for (int t = 0; t <= tq; ++t) {
        const int k0t = t * 64;
        // global loads into regs
        bf16x8 kv[2], vh[2], vl[2];
        #pragma unroll
        for (int p = 0; p < 2; ++p)
            kv[p] = *(const bf16x8*)(Kb + (size_t)(k0t + krow + p * 32) * HD_ + kch * 8);
        #pragma unroll
        for (int c = 0; c < 2; ++c) {
            vh[c] = *(const bf16x8*)(Vhb + (size_t)(k0t + vkey) * HD_ + vb + c * 8);
            vl[c] = *(const bf16x8*)(Vlb + (size_t)(k0t + vkey) * HD_ + vb + c * 8);
        }
        __syncthreads();   // (A) prior iteration's LDS reads complete
        #pragma unroll
        for (int p = 0; p < 2; ++p)
            *(bf16x8*)&Ks[krow + p * 32][kch * 8] = kv[p];
        #pragma unroll
        for (int c = 0; c < 2; ++c)
            #pragma unroll
            for (int j = 0; j < 8; ++j) {
                Vthi[vb + c * 8 + j][vkey] = (u16)vh[c][j];
                Vtlo[vb + c * 8 + j][vkey] = (u16)vl[c][j];
            }
        __syncthreads();   // (B) tiles visible

        // ---- S = Q K^T ----
        f32x4 sf[4];
        #pragma unroll
        for (int n = 0; n < 4; ++n) sf[n] = (f32x4){0.f, 0.f, 0.f, 0.f};
        #pragma unroll
        for (int ch = 0; ch < 2; ++ch)
            #pragma unroll
            for (int n = 0; n < 4; ++n) {
                bf16x8 bk = *(const bf16x8*)&Ks[n * 16 + lr][ch * 32 + quad * 8];
                sf[n] = __builtin_amdgcn_mfma_f32_16x16x32_bf16(qf[ch], bk, sf[n], 0, 0, 0);
            }

        // ---- scale + zero-mask (only the diagonal tile has masked cols) ----
        if (t == tq) {
            #pragma unroll
            for (int n = 0; n < 4; ++n)
                #pragma unroll
                for (int i = 0; i < 4; ++i) {
                    int ig = q0 + w * 16 + quad * 4 + i;
                    int jg = k0t + n * 16 + lr;
                    float val = sf[n][i];
                    sf[n][i] = (jg <= ig) ? val * SCALE_ : 0.f;
                }
        } else {
            #pragma unroll
            for (int n = 0; n < 4; ++n) sf[n] *= SCALE_;
        }

        // ---- online softmax (rows = quad*4+i, cols across 16 lanes x 4 grps) ----
        #pragma unroll
        for (int i = 0; i < 4; ++i) {
            float mx = fmaxf(fmaxf(sf[0][i], sf[1][i]), fmaxf(sf[2][i], sf[3][i]));
            mx = fmaxf(mx, __shfl_xor(mx, 1));
            mx = fmaxf(mx, __shfl_xor(mx, 2));
            mx = fmaxf(mx, __shfl_xor(mx, 4));
            mx = fmaxf(mx, __shfl_xor(mx, 8));
            float mn    = fmaxf(m_i[i], mx);
            float alpha = __expf(m_i[i] - mn);
            m_i[i] = mn;
            float ps = 0.f;
            #pragma unroll
            for (int n = 0; n < 4; ++n) {
                float p = __expf(sf[n][i] - mn);
                sf[n][i] = p;
                ps += p;
            }
            ps += __shfl_xor(ps, 1); ps += __shfl_xor(ps, 2);
            ps += __shfl_xor(ps, 4); ps += __shfl_xor(ps, 8);
            l_i[i] = l_i[i] * alpha + ps;
            #pragma unroll
            for (int n = 0; n < 4; ++n) of[n][i] *= alpha;
        }

        // ---- P -> LDS (hi/lo), band-local: no cross-wave hazard ----
        #pragma unroll
        for (int n = 0; n < 4; ++n)
            #pragma unroll
            for (int i = 0; i < 4; ++i) {
                float p = sf[n][i];
                u16 ph = f2bf(p);
                Phi[w * 16 + quad * 4 + i][n * 16 + lr] = ph;
                Plo[w * 16 + quad * 4 + i][n * 16 + lr] = f2bf(p - bf2f(ph));
            }

        // ---- O += P V  (A = P band rows, B = V^T) ----
        #pragma unroll
        for (int ch = 0; ch < 2; ++ch) {
            bf16x8 pah = *(const bf16x8*)&Phi[w * 16 + lr][ch * 32 + quad * 8];
            bf16x8 pal = *(const bf16x8*)&Plo[w * 16 + lr][ch * 32 + quad * 8];
            #pragma unroll
            for (int n = 0; n < 4; ++n) {
                bf16x8 bvh = *(const bf16x8*)&Vthi[n * 16 + lr][ch * 32 + quad * 8];
                bf16x8 bvl = *(const bf16x8*)&Vtlo[n * 16 + lr][ch * 32 + quad * 8];
                of[n] = __builtin_amdgcn_mfma_f32_16x16x32_bf16(pah, bvh, of[n], 0, 0, 0);
                of[n] = __builtin_amdgcn_mfma_f32_16x16x32_bf16(pah, bvl, of[n], 0, 0, 0);
                of[n] = __builtin_amdgcn_mfma_f32_16x16x32_bf16(pal, bvh, of[n], 0, 0, 0);
            }
        }
    }

    // ---- masked-suffix contribution + normalize + store ----
    const int cnt = S_ - (q0 + 64);
    const float* suf = SUF + ((size_t)bh * (NT_ + 1) + (tq + 1)) * HD_;
    float sv[4];
    #pragma unroll
    for (int n = 0; n < 4; ++n) sv[n] = suf[n * 16 + lr];

    #pragma unroll
    for (int i = 0; i < 4; ++i) {
        float we    = __expf(-m_i[i]);
        float denom = l_i[i] + we * (float)cnt;
        float inv   = 1.0f / denom;
        int   row   = q0 + w * 16 + quad * 4 + i;
        #pragma unroll
        for (int n = 0; n < 4; ++n) {
            int vd = n * 16 + lr;
            OUT[((size_t)b * S_ + row) * D_ + h * HD_ + vd] =
                (of[n][i] + we * sv[n]) * inv;
        }
    }
}

// ---------------------------------------------------------------------------
extern "C" void kernel_launch(void* const* d_in, const int* in_sizes, int n_in,
                              void* d_out, int out_size, void* d_ws, size_t ws_size,
                              hipStream_t stream)
{
    (void)in_sizes; (void)n_in; (void)out_size; (void)ws_size;
    const float* q  = (const float*)d_in[0];
    const float* k  = (const float*)d_in[1];
    const float* v  = (const float*)d_in[2];
    const float* wq = (const float*)d_in[3];
    const float* wk = (const float*)d_in[4];
    const float* wv = (const float*)d_in[5];
    float* out = (float*)d_out;

    const size_t PROJ = (size_t)B_ * H_ * S_ * HD_;     // 4,194,304 elems
    u16* QP   = (u16*)d_ws;
    u16* KP   = QP + PROJ;
    u16* VPhi = KP + PROJ;
    u16* VPlo = VPhi + PROJ;
    float* TS  = (float*)(VPlo + PROJ);
    float* SUF = TS + (size_t)B_ * H_ * NT_ * HD_;

    proj_mfma<<<dim3(D_ / 64, (B_ * S_) / 64, 3), 256, 0, stream>>>(
        q, k, v, wq, wk, wv, QP, KP, VPhi, VPlo);
    vtilesum_kernel<<<dim3(NT_, B_ * H_), 64, 0, stream>>>(VPhi, VPlo, TS);
    vsuffix_kernel<<<B_ * H_, 64, 0, stream>>>(TS, SUF);
    attn_mfma<<<dim3(NT_, B_ * H_), 256, 0, stream>>>(QP, KP, VPhi, VPlo, SUF, out);
}